// Round 7
// baseline (358.811 us; speedup 1.0000x reference)
//
#include <hip/hip_runtime.h>
#include <hip/hip_bf16.h>
#include <math.h>

// Problem constants
constexpr int T_ = 512;
constexpr int B_ = 4;
constexpr int E_ = 1024;
constexpr int H_ = 16;
constexpr int NGRAM_ = 2;
constexpr int TGT_ = (1 + NGRAM_) * T_;   // 1536
constexpr int ROWS_ = TGT_ * B_;          // 6144

typedef __bf16 bf16_t;
typedef __bf16 bf16x8 __attribute__((ext_vector_type(8)));
typedef __bf16 bf16x4 __attribute__((ext_vector_type(4)));
typedef float f32x4 __attribute__((ext_vector_type(4)));

#define GLL(gaddr, laddr)                                                     \
  __builtin_amdgcn_global_load_lds(                                           \
      (const __attribute__((address_space(1))) void*)(gaddr),                 \
      (__attribute__((address_space(3))) void*)(laddr), 16, 0, 0)

// ---------------------------------------------------------------------------
// prep: all fp32->bf16 conversions + Toeplitz bucket LUT build, one launch.
// ---------------------------------------------------------------------------
__global__ __launch_bounds__(256) void prep(
    const float* __restrict__ query, const float* __restrict__ ipw,
    const float* __restrict__ relw, const float* __restrict__ outw,
    bf16_t* __restrict__ qb, bf16_t* __restrict__ ipwb,
    bf16_t* __restrict__ relwb, bf16_t* __restrict__ outwb,
    const int* __restrict__ mbuck, const int* __restrict__ pbuck,
    unsigned char* __restrict__ lutM, unsigned char* __restrict__ lutP) {
  const int i = blockIdx.x * 256 + threadIdx.x;
  if (i < 512) {
    lutM[i] = (unsigned char)mbuck[(size_t)i * T_];        // f(-i)
    lutP[i] = (unsigned char)pbuck[(size_t)i * (2 * T_)];  // f(-(i+1))
  }
  constexpr int N1 = ROWS_ * E_ / 4;
  constexpr int N2 = 3 * E_ * E_ / 4;
  constexpr int N3 = 512 * E_ / 4;
  constexpr int N4 = E_ * E_ / 4;
  const float4* src;
  bf16_t* dst;
  int j = i;
  if (i < N1) { src = (const float4*)query; dst = qb; }
  else if (i < N1 + N2) { src = (const float4*)ipw; dst = ipwb; j = i - N1; }
  else if (i < N1 + N2 + N3) { src = (const float4*)relw; dst = relwb; j = i - N1 - N2; }
  else if (i < N1 + N2 + N3 + N4) { src = (const float4*)outw; dst = outwb; j = i - N1 - N2 - N3; }
  else return;
  const float4 v = src[j];
  bf16x4 o;
  o[0] = (bf16_t)v.x; o[1] = (bf16_t)v.y;
  o[2] = (bf16_t)v.z; o[3] = (bf16_t)v.w;
  ((bf16x4*)dst)[j] = o;
}

// ---------------------------------------------------------------------------
// Transpose V stream: vT[bh][d][token] <- qkvb[token*B+b][2048 + h*64 + d]
// ---------------------------------------------------------------------------
__global__ __launch_bounds__(256) void transpose_v(
    const bf16_t* __restrict__ qkvb, bf16_t* __restrict__ vT) {
  __shared__ bf16_t tile[64][72];
  const int tb = blockIdx.x;
  const int bh = blockIdx.y;
  const int b = bh >> 4, h = bh & 15;
  const int tid = threadIdx.x;
  const int tau0 = tb * 64;
#pragma unroll
  for (int u = 0; u < 2; ++u) {
    const int c = u * 256 + tid;
    const int r = c >> 3, kc = c & 7;
    *(uint4*)&tile[r][kc * 8] = *(const uint4*)
        &qkvb[((size_t)(tau0 + r) * B_ + b) * 3072 + 2048 + h * 64 + kc * 8];
  }
  __syncthreads();
#pragma unroll
  for (int u = 0; u < 2; ++u) {
    const int c = u * 256 + tid;
    const int d = c >> 3, tc = c & 7;
    bf16x8 v;
#pragma unroll
    for (int i = 0; i < 8; ++i) v[i] = tile[tc * 8 + i][d];
    *(bf16x8*)&vT[((size_t)bh * 64 + d) * (size_t)TGT_ + tau0 + tc * 8] = v;
  }
}

// ---------------------------------------------------------------------------
// Combined projection GEMM: A[6144][1024] bf16, W[3584][1024] bf16
// (rows 0..3071 = in_proj, 3072..3583 = rel). BK=64, XOR-swizzled LDS,
// global_load_lds staging.
// ---------------------------------------------------------------------------
__global__ __launch_bounds__(256, 4) void bgemm_proj(
    const bf16_t* __restrict__ A, const bf16_t* __restrict__ W,
    const float* __restrict__ ipb, const float* __restrict__ relb,
    bf16_t* __restrict__ qkvb, float* __restrict__ relv2) {
  __shared__ bf16_t As[128 * 64];
  __shared__ bf16_t Bs[128 * 64];

  const int tid = threadIdx.x;
  const int wave = tid >> 6, lane = tid & 63;
  const int wr = wave >> 1, wc = wave & 1;
  const int bm = blockIdx.y * 128, bn = blockIdx.x * 128;
  const int q = lane >> 4, ln = lane & 15;
  const int grow = tid >> 3;
  const int gcol = ((tid & 7) ^ (grow & 7)) * 8;

  f32x4 acc[4][4];
#pragma unroll
  for (int mi = 0; mi < 4; ++mi)
#pragma unroll
    for (int ni = 0; ni < 4; ++ni)
#pragma unroll
      for (int r = 0; r < 4; ++r) acc[mi][ni][r] = 0.f;

  const int co[2] = {((q) ^ (ln & 7)) * 8, ((4 + q) ^ (ln & 7)) * 8};

  for (int k0 = 0; k0 < 1024; k0 += 64) {
    __syncthreads();
#pragma unroll
    for (int p = 0; p < 4; ++p) {
      GLL(&A[(size_t)(bm + p * 32 + grow) * 1024 + k0 + gcol], &As[p * 2048 + tid * 8]);
      GLL(&W[(size_t)(bn + p * 32 + grow) * 1024 + k0 + gcol], &Bs[p * 2048 + tid * 8]);
    }
    __syncthreads();
#pragma unroll
    for (int t = 0; t < 2; ++t) {
      bf16x8 af[4], bf[4];
#pragma unroll
      for (int mi = 0; mi < 4; ++mi)
        af[mi] = *(const bf16x8*)&As[(wr * 64 + mi * 16 + ln) * 64 + co[t]];
#pragma unroll
      for (int ni = 0; ni < 4; ++ni)
        bf[ni] = *(const bf16x8*)&Bs[(wc * 64 + ni * 16 + ln) * 64 + co[t]];
#pragma unroll
      for (int mi = 0; mi < 4; ++mi)
#pragma unroll
        for (int ni = 0; ni < 4; ++ni)
          acc[mi][ni] = __builtin_amdgcn_mfma_f32_16x16x32_bf16(
              af[mi], bf[ni], acc[mi][ni], 0, 0, 0);
    }
  }

  if (bn < 3072) {
    const float sc = (bn < 1024) ? 0.125f : 1.0f;
#pragma unroll
    for (int mi = 0; mi < 4; ++mi) {
#pragma unroll
      for (int ni = 0; ni < 4; ++ni) {
        const int col = bn + wc * 64 + ni * 16 + ln;
        const float bv = ipb[col];
#pragma unroll
        for (int r = 0; r < 4; ++r) {
          const int row = bm + wr * 64 + mi * 16 + q * 4 + r;
          qkvb[(size_t)row * 3072 + col] = (bf16_t)((acc[mi][ni][r] + bv) * sc);
        }
      }
    }
  } else {
    const int cb = bn - 3072 + wc * 64;
    float4 rb4;
#pragma unroll
    for (int ni = 0; ni < 4; ++ni)
      ((float*)&rb4)[ni] = relb[cb + ni * 16 + ln];
    const int bkbase = cb >> 4;
#pragma unroll
    for (int mi = 0; mi < 4; ++mi) {
#pragma unroll
      for (int r = 0; r < 4; ++r) {
        const int row = bm + wr * 64 + mi * 16 + q * 4 + r;
        float4 v;
        v.x = acc[mi][0][r] + rb4.x;
        v.y = acc[mi][1][r] + rb4.y;
        v.z = acc[mi][2][r] + rb4.z;
        v.w = acc[mi][3][r] + rb4.w;
        *(float4*)&relv2[(size_t)row * 512 + ln * 32 + bkbase] = v;
      }
    }
  }
}

// ---------------------------------------------------------------------------
// Output projection GEMM (fp32 out), same BK=64 swizzled structure.
// ---------------------------------------------------------------------------
__global__ __launch_bounds__(256, 4) void bgemm_out(
    const bf16_t* __restrict__ A, const bf16_t* __restrict__ W,
    const float* __restrict__ bias, float* __restrict__ C, int N) {
  __shared__ bf16_t As[128 * 64];
  __shared__ bf16_t Bs[128 * 64];

  const int tid = threadIdx.x;
  const int wave = tid >> 6, lane = tid & 63;
  const int wr = wave >> 1, wc = wave & 1;
  const int bm = blockIdx.y * 128, bn = blockIdx.x * 128;
  const int q = lane >> 4, ln = lane & 15;
  const int grow = tid >> 3;
  const int gcol = ((tid & 7) ^ (grow & 7)) * 8;

  f32x4 acc[4][4];
#pragma unroll
  for (int mi = 0; mi < 4; ++mi)
#pragma unroll
    for (int ni = 0; ni < 4; ++ni)
#pragma unroll
      for (int r = 0; r < 4; ++r) acc[mi][ni][r] = 0.f;

  const int co[2] = {((q) ^ (ln & 7)) * 8, ((4 + q) ^ (ln & 7)) * 8};

  for (int k0 = 0; k0 < 1024; k0 += 64) {
    __syncthreads();
#pragma unroll
    for (int p = 0; p < 4; ++p) {
      GLL(&A[(size_t)(bm + p * 32 + grow) * 1024 + k0 + gcol], &As[p * 2048 + tid * 8]);
      GLL(&W[(size_t)(bn + p * 32 + grow) * 1024 + k0 + gcol], &Bs[p * 2048 + tid * 8]);
    }
    __syncthreads();
#pragma unroll
    for (int t = 0; t < 2; ++t) {
      bf16x8 af[4], bf[4];
#pragma unroll
      for (int mi = 0; mi < 4; ++mi)
        af[mi] = *(const bf16x8*)&As[(wr * 64 + mi * 16 + ln) * 64 + co[t]];
#pragma unroll
      for (int ni = 0; ni < 4; ++ni)
        bf[ni] = *(const bf16x8*)&Bs[(wc * 64 + ni * 16 + ln) * 64 + co[t]];
#pragma unroll
      for (int mi = 0; mi < 4; ++mi)
#pragma unroll
        for (int ni = 0; ni < 4; ++ni)
          acc[mi][ni] = __builtin_amdgcn_mfma_f32_16x16x32_bf16(
              af[mi], bf[ni], acc[mi][ni], 0, 0, 0);
    }
  }

#pragma unroll
  for (int mi = 0; mi < 4; ++mi) {
#pragma unroll
    for (int ni = 0; ni < 4; ++ni) {
      const int col = bn + wc * 64 + ni * 16 + ln;
      const float bv = bias[col];
#pragma unroll
      for (int r = 0; r < 4; ++r) {
        const int row = bm + wr * 64 + mi * 16 + q * 4 + r;
        C[(size_t)row * N + col] = acc[mi][ni][r] + bv;
      }
    }
  }
}

// ---------------------------------------------------------------------------
// MFMA flash attention, all three streams merged per block.
// Grid (8, 64): qt = 7 - blockIdx.x (long blocks first), bh = blockIdx.y.
// For s<T the three streams share K/V tiles -> staged ONCE, used 3x.
// Two small diagonal tiles (z=1,2 predict keys) appended to the K loop.
// Fixed-shift softmax (scores O(+-5): exp exact, masked lanes contribute 0).
// LDS ~38 KB -> 4 blocks/CU. Q staged through Ks buffer at startup.
// ---------------------------------------------------------------------------
__global__ __launch_bounds__(256, 4) void flash_mfma(
    const bf16_t* __restrict__ qkvb, const bf16_t* __restrict__ vT,
    const float* __restrict__ relv2,
    const unsigned char* __restrict__ lutM, const unsigned char* __restrict__ lutP,
    bf16_t* __restrict__ attn) {
  __shared__ bf16_t Ks[64 * 64];
  __shared__ bf16_t Vts[64 * 64];
  __shared__ bf16_t Ps[4][16 * 64];
  __shared__ bf16_t biasS[3][64 * 33];
  __shared__ unsigned char lutMs[512];
  __shared__ unsigned char lutPs[512];

  const int qt = 7 - blockIdx.x, tq0 = qt * 64;
  const int bh = blockIdx.y, b = bh >> 4, h = bh & 15;
  const int tid = threadIdx.x;
  const int wave = tid >> 6, lane = tid & 63;
  const int q = lane >> 4, ln = lane & 15;
  const int m0 = wave * 16;
  const int grow = tid >> 3;
  const int gcol = ((tid & 7) ^ (grow & 7)) * 8;
  const int co[2] = {((q) ^ (ln & 7)) * 8, ((4 + q) ^ (ln & 7)) * 8};

  if (tid < 128) ((int*)lutMs)[tid] = ((const int*)lutM)[tid];
  else if (tid < 256) ((int*)lutPs)[tid - 128] = ((const int*)lutP)[tid - 128];

  // stage bias tables for all 3 streams (bf16, [z][row][bucket])
#pragma unroll
  for (int z = 0; z < 3; ++z) {
#pragma unroll
    for (int u = 0; u < 2; ++u) {
      const int c = u * 256 + tid;
      const int row = c >> 3, j4 = (c & 7) * 4;
      const float4 v = *(const float4*)
          &relv2[((size_t)(z * T_ + tq0 + row) * B_ + b) * 512 + h * 32 + j4];
      biasS[z][row * 33 + j4 + 0] = (bf16_t)v.x;
      biasS[z][row * 33 + j4 + 1] = (bf16_t)v.y;
      biasS[z][row * 33 + j4 + 2] = (bf16_t)v.z;
      biasS[z][row * 33 + j4 + 3] = (bf16_t)v.w;
    }
  }

  // stage Q for each stream through the Ks buffer, keep fragments in regs
  bf16x8 aq[3][2];
#pragma unroll
  for (int z = 0; z < 3; ++z) {
    __syncthreads();  // Ks free (also publishes biasS on z=0)
#pragma unroll
    for (int u = 0; u < 2; ++u) {
      const int sr = u * 32 + grow;
      GLL(&qkvb[((size_t)(z * T_ + tq0 + sr) * B_ + b) * 3072 + h * 64 + gcol],
          &Ks[u * 2048 + tid * 8]);
    }
    __syncthreads();
    aq[z][0] = *(const bf16x8*)&Ks[(m0 + ln) * 64 + co[0]];
    aq[z][1] = *(const bf16x8*)&Ks[(m0 + ln) * 64 + co[1]];
  }

  f32x4 Od[3][4];
  float lpart[3][4];
#pragma unroll
  for (int z = 0; z < 3; ++z)
#pragma unroll
    for (int r = 0; r < 4; ++r) {
      lpart[z][r] = 0.f;
#pragma unroll
      for (int tc = 0; tc < 4; ++tc) Od[z][tc][r] = 0.f;
    }

  const int ntiles = qt + 3;  // qt+1 shared main tiles + 2 diagonal tiles

  for (int j = 0; j < ntiles; ++j) {
    const int ze = j - qt;            // >0 -> diagonal tile for stream ze
    const int krb = (ze > 0) ? (ze * T_ + tq0) : j * 64;

    __syncthreads();  // prev tile consumers done with Ks/Vts
#pragma unroll
    for (int u = 0; u < 2; ++u) {
      const int sr = u * 32 + grow;
      GLL(&qkvb[((size_t)(krb + sr) * B_ + b) * 3072 + 1024 + h * 64 + gcol],
          &Ks[u * 2048 + tid * 8]);
      GLL(&vT[((size_t)bh * 64 + sr) * (size_t)TGT_ + krb + gcol],
          &Vts[u * 2048 + tid * 8]);
    }
    __syncthreads();

    const int zlo = (ze > 0) ? ze : 0;
    const int zhi = (ze > 0) ? ze : 2;
    for (int z = zlo; z <= zhi; ++z) {
      // QK^T for stream z
      f32x4 acc[4];
#pragma unroll
      for (int tc = 0; tc < 4; ++tc)
#pragma unroll
        for (int r = 0; r < 4; ++r) acc[tc][r] = 0.f;
#pragma unroll
      for (int tc = 0; tc < 4; ++tc) {
        const bf16x8 b0 = *(const bf16x8*)&Ks[(tc * 16 + ln) * 64 + co[0]];
        acc[tc] = __builtin_amdgcn_mfma_f32_16x16x32_bf16(aq[z][0], b0, acc[tc], 0, 0, 0);
        const bf16x8 b1 = *(const bf16x8*)&Ks[(tc * 16 + ln) * 64 + co[1]];
        acc[tc] = __builtin_amdgcn_mfma_f32_16x16x32_bf16(aq[z][1], b1, acc[tc], 0, 0, 0);
      }

      // bias + mask + exp; write P (swizzled) into own-wave buffer
#pragma unroll
      for (int r = 0; r < 4; ++r) {
        const int rloc = m0 + q * 4 + r;
#pragma unroll
        for (int tc = 0; tc < 4; ++tc) {
          const int sl = tc * 16 + ln;
          bool valid;
          float bv;
          if (ze <= 0) {
            valid = (j < qt) | (sl <= rloc);
            int d = tq0 + rloc - (j * 64 + sl);
            d = d < 0 ? 0 : d;
            bv = (float)biasS[z][rloc * 33 + (int)(z == 0 ? lutMs[d] : lutPs[d])];
          } else {
            valid = (sl == rloc);
            bv = (float)biasS[z][rloc * 33];  // bucket(0) == 0
          }
          const float p = valid ? __expf(acc[tc][r] + bv) : 0.f;
          lpart[z][r] += p;
          const int pc = (tc * 2 + (ln >> 3)) ^ ((q * 4 + r) & 7);
          Ps[wave][(q * 4 + r) * 64 + pc * 8 + (ln & 7)] = (bf16_t)p;
        }
      }

      // O += P V (own-wave Ps: same-wave LDS ordering, no barrier)
      bf16x8 ap[2];
      ap[0] = *(const bf16x8*)&Ps[wave][ln * 64 + co[0]];
      ap[1] = *(const bf16x8*)&Ps[wave][ln * 64 + co[1]];
#pragma unroll
      for (int tc = 0; tc < 4; ++tc) {
        const bf16x8 v0 = *(const bf16x8*)&Vts[(tc * 16 + ln) * 64 + co[0]];
        Od[z][tc] = __builtin_amdgcn_mfma_f32_16x16x32_bf16(ap[0], v0, Od[z][tc], 0, 0, 0);
        const bf16x8 v1 = *(const bf16x8*)&Vts[(tc * 16 + ln) * 64 + co[1]];
        Od[z][tc] = __builtin_amdgcn_mfma_f32_16x16x32_bf16(ap[1], v1, Od[z][tc], 0, 0, 0);
      }
    }
  }

  // epilogue: reduce row sums, normalize, store (per stream)
#pragma unroll
  for (int z = 0; z < 3; ++z) {
#pragma unroll
    for (int r = 0; r < 4; ++r) {
      float l = lpart[z][r];
      l += __shfl_xor(l, 1, 16);
      l += __shfl_xor(l, 2, 16);
      l += __shfl_xor(l, 4, 16);
      l += __shfl_xor(l, 8, 16);
      const float inv = 1.f / l;
      const size_t rowbase =
          ((size_t)(z * T_ + tq0 + m0 + q * 4 + r) * B_ + b) * (size_t)E_ + h * 64;
#pragma unroll
      for (int tc = 0; tc < 4; ++tc)
        attn[rowbase + tc * 16 + ln] = (bf16_t)(Od[z][tc][r] * inv);
    }
  }
}

// ---------------------------------------------------------------------------
extern "C" void kernel_launch(void* const* d_in, const int* in_sizes, int n_in,
                              void* d_out, int out_size, void* d_ws, size_t ws_size,
                              hipStream_t stream) {
  const float* query = (const float*)d_in[0];
  const float* ipw   = (const float*)d_in[1];
  const float* ipb   = (const float*)d_in[2];
  const float* relw  = (const float*)d_in[3];
  const float* relb  = (const float*)d_in[4];
  const float* outw  = (const float*)d_in[5];
  const float* outb  = (const float*)d_in[6];
  const int*   mbuck = (const int*)d_in[7];
  const int*   pbuck = (const int*)d_in[8];
  float* out = (float*)d_out;

  // workspace layout (ipwb and relwb adjacent -> combined [3584][1024] W)
  bf16_t* qkvb  = (bf16_t*)d_ws;                                 // 6144x3072
  float*  relv2 = (float*)(qkvb + (size_t)ROWS_ * 3 * E_);       // 6144x512 f32
  bf16_t* qb    = (bf16_t*)(relv2 + (size_t)ROWS_ * 512);        // 6144x1024
  bf16_t* ipwb  = qb + (size_t)ROWS_ * E_;                       // 3072x1024
  bf16_t* relwb = ipwb + (size_t)(3 * E_) * E_;                  // 512x1024 (adjacent!)
  bf16_t* outwb = relwb + (size_t)512 * E_;                      // 1024x1024
  bf16_t* attnb = outwb + (size_t)E_ * E_;                       // 6144x1024
  unsigned char* lutM = (unsigned char*)(attnb + (size_t)ROWS_ * E_);
  unsigned char* lutP = lutM + 512;
  bf16_t* vT = (bf16_t*)(lutP + 512);                            // 64x64x1536

  const dim3 blk(256);

  // 1) conversions + LUTs
  {
    const int ntot = (ROWS_ * E_ + 3 * E_ * E_ + 512 * E_ + E_ * E_) / 4;
    prep<<<dim3((ntot + 255) / 256), blk, 0, stream>>>(
        query, ipw, relw, outw, qb, ipwb, relwb, outwb, mbuck, pbuck, lutM, lutP);
  }

  // 2) combined QKV + rel projection
  bgemm_proj<<<dim3(3584 / 128, ROWS_ / 128), blk, 0, stream>>>(
      qb, ipwb, ipb, relb, qkvb, relv2);

  // 3) V stream transpose
  transpose_v<<<dim3(TGT_ / 64, B_ * H_), blk, 0, stream>>>(qkvb, vT);

  // 4) flash attention, all streams merged
  flash_mfma<<<dim3(8, B_ * H_), blk, 0, stream>>>(
      qkvb, vT, relv2, lutM, lutP, attnb);

  // 5) output projection
  bgemm_out<<<dim3(E_ / 128, ROWS_ / 128), blk, 0, stream>>>(
      attnb, outwb, outb, out, E_);
}

// Round 8
// 255.512 us; speedup vs baseline: 1.4043x; 1.4043x over previous
//
#include <hip/hip_runtime.h>
#include <hip/hip_bf16.h>
#include <math.h>

// Problem constants
constexpr int T_ = 512;
constexpr int B_ = 4;
constexpr int E_ = 1024;
constexpr int H_ = 16;
constexpr int NGRAM_ = 2;
constexpr int TGT_ = (1 + NGRAM_) * T_;   // 1536
constexpr int ROWS_ = TGT_ * B_;          // 6144

typedef __bf16 bf16_t;
typedef __bf16 bf16x8 __attribute__((ext_vector_type(8)));
typedef __bf16 bf16x4 __attribute__((ext_vector_type(4)));
typedef float f32x4 __attribute__((ext_vector_type(4)));

#define GLL(gaddr, laddr)                                                     \
  __builtin_amdgcn_global_load_lds(                                           \
      (const __attribute__((address_space(1))) void*)(gaddr),                 \
      (__attribute__((address_space(3))) void*)(laddr), 16, 0, 0)

// ---------------------------------------------------------------------------
// prep: all fp32->bf16 conversions + Toeplitz bucket LUT build, one launch.
// ---------------------------------------------------------------------------
__global__ __launch_bounds__(256) void prep(
    const float* __restrict__ query, const float* __restrict__ ipw,
    const float* __restrict__ relw, const float* __restrict__ outw,
    bf16_t* __restrict__ qb, bf16_t* __restrict__ ipwb,
    bf16_t* __restrict__ relwb, bf16_t* __restrict__ outwb,
    const int* __restrict__ mbuck, const int* __restrict__ pbuck,
    unsigned char* __restrict__ lutM, unsigned char* __restrict__ lutP) {
  const int i = blockIdx.x * 256 + threadIdx.x;
  if (i < 512) {
    lutM[i] = (unsigned char)mbuck[(size_t)i * T_];        // f(-i)
    lutP[i] = (unsigned char)pbuck[(size_t)i * (2 * T_)];  // f(-(i+1))
  }
  constexpr int N1 = ROWS_ * E_ / 4;
  constexpr int N2 = 3 * E_ * E_ / 4;
  constexpr int N3 = 512 * E_ / 4;
  constexpr int N4 = E_ * E_ / 4;
  const float4* src;
  bf16_t* dst;
  int j = i;
  if (i < N1) { src = (const float4*)query; dst = qb; }
  else if (i < N1 + N2) { src = (const float4*)ipw; dst = ipwb; j = i - N1; }
  else if (i < N1 + N2 + N3) { src = (const float4*)relw; dst = relwb; j = i - N1 - N2; }
  else if (i < N1 + N2 + N3 + N4) { src = (const float4*)outw; dst = outwb; j = i - N1 - N2 - N3; }
  else return;
  const float4 v = src[j];
  bf16x4 o;
  o[0] = (bf16_t)v.x; o[1] = (bf16_t)v.y;
  o[2] = (bf16_t)v.z; o[3] = (bf16_t)v.w;
  ((bf16x4*)dst)[j] = o;
}

// ---------------------------------------------------------------------------
// Transpose V stream: vT[bh][d][token] <- qkvb[token*B+b][2048 + h*64 + d]
// ---------------------------------------------------------------------------
__global__ __launch_bounds__(256) void transpose_v(
    const bf16_t* __restrict__ qkvb, bf16_t* __restrict__ vT) {
  __shared__ bf16_t tile[64][72];
  const int tb = blockIdx.x;
  const int bh = blockIdx.y;
  const int b = bh >> 4, h = bh & 15;
  const int tid = threadIdx.x;
  const int tau0 = tb * 64;
#pragma unroll
  for (int u = 0; u < 2; ++u) {
    const int c = u * 256 + tid;
    const int r = c >> 3, kc = c & 7;
    *(uint4*)&tile[r][kc * 8] = *(const uint4*)
        &qkvb[((size_t)(tau0 + r) * B_ + b) * 3072 + 2048 + h * 64 + kc * 8];
  }
  __syncthreads();
#pragma unroll
  for (int u = 0; u < 2; ++u) {
    const int c = u * 256 + tid;
    const int d = c >> 3, tc = c & 7;
    bf16x8 v;
#pragma unroll
    for (int i = 0; i < 8; ++i) v[i] = tile[tc * 8 + i][d];
    *(bf16x8*)&vT[((size_t)bh * 64 + d) * (size_t)TGT_ + tau0 + tc * 8] = v;
  }
}

// ---------------------------------------------------------------------------
// Combined projection GEMM: A[6144][1024] bf16, W[3584][1024] bf16
// (rows 0..3071 = in_proj, 3072..3583 = rel). BK=64, XOR-swizzled LDS,
// global_load_lds staging.
// ---------------------------------------------------------------------------
__global__ __launch_bounds__(256, 4) void bgemm_proj(
    const bf16_t* __restrict__ A, const bf16_t* __restrict__ W,
    const float* __restrict__ ipb, const float* __restrict__ relb,
    bf16_t* __restrict__ qkvb, float* __restrict__ relv2) {
  __shared__ bf16_t As[128 * 64];
  __shared__ bf16_t Bs[128 * 64];

  const int tid = threadIdx.x;
  const int wave = tid >> 6, lane = tid & 63;
  const int wr = wave >> 1, wc = wave & 1;
  const int bm = blockIdx.y * 128, bn = blockIdx.x * 128;
  const int q = lane >> 4, ln = lane & 15;
  const int grow = tid >> 3;
  const int gcol = ((tid & 7) ^ (grow & 7)) * 8;

  f32x4 acc[4][4];
#pragma unroll
  for (int mi = 0; mi < 4; ++mi)
#pragma unroll
    for (int ni = 0; ni < 4; ++ni)
#pragma unroll
      for (int r = 0; r < 4; ++r) acc[mi][ni][r] = 0.f;

  const int co[2] = {((q) ^ (ln & 7)) * 8, ((4 + q) ^ (ln & 7)) * 8};

  for (int k0 = 0; k0 < 1024; k0 += 64) {
    __syncthreads();
#pragma unroll
    for (int p = 0; p < 4; ++p) {
      GLL(&A[(size_t)(bm + p * 32 + grow) * 1024 + k0 + gcol], &As[p * 2048 + tid * 8]);
      GLL(&W[(size_t)(bn + p * 32 + grow) * 1024 + k0 + gcol], &Bs[p * 2048 + tid * 8]);
    }
    __syncthreads();
#pragma unroll
    for (int t = 0; t < 2; ++t) {
      bf16x8 af[4], bf[4];
#pragma unroll
      for (int mi = 0; mi < 4; ++mi)
        af[mi] = *(const bf16x8*)&As[(wr * 64 + mi * 16 + ln) * 64 + co[t]];
#pragma unroll
      for (int ni = 0; ni < 4; ++ni)
        bf[ni] = *(const bf16x8*)&Bs[(wc * 64 + ni * 16 + ln) * 64 + co[t]];
#pragma unroll
      for (int mi = 0; mi < 4; ++mi)
#pragma unroll
        for (int ni = 0; ni < 4; ++ni)
          acc[mi][ni] = __builtin_amdgcn_mfma_f32_16x16x32_bf16(
              af[mi], bf[ni], acc[mi][ni], 0, 0, 0);
    }
  }

  if (bn < 3072) {
    const float sc = (bn < 1024) ? 0.125f : 1.0f;
#pragma unroll
    for (int mi = 0; mi < 4; ++mi) {
#pragma unroll
      for (int ni = 0; ni < 4; ++ni) {
        const int col = bn + wc * 64 + ni * 16 + ln;
        const float bv = ipb[col];
#pragma unroll
        for (int r = 0; r < 4; ++r) {
          const int row = bm + wr * 64 + mi * 16 + q * 4 + r;
          qkvb[(size_t)row * 3072 + col] = (bf16_t)((acc[mi][ni][r] + bv) * sc);
        }
      }
    }
  } else {
    const int cb = bn - 3072 + wc * 64;
    float4 rb4;
#pragma unroll
    for (int ni = 0; ni < 4; ++ni)
      ((float*)&rb4)[ni] = relb[cb + ni * 16 + ln];
    const int bkbase = cb >> 4;
#pragma unroll
    for (int mi = 0; mi < 4; ++mi) {
#pragma unroll
      for (int r = 0; r < 4; ++r) {
        const int row = bm + wr * 64 + mi * 16 + q * 4 + r;
        float4 v;
        v.x = acc[mi][0][r] + rb4.x;
        v.y = acc[mi][1][r] + rb4.y;
        v.z = acc[mi][2][r] + rb4.z;
        v.w = acc[mi][3][r] + rb4.w;
        *(float4*)&relv2[(size_t)row * 512 + ln * 32 + bkbase] = v;
      }
    }
  }
}

// ---------------------------------------------------------------------------
// Output projection GEMM (fp32 out), same BK=64 swizzled structure.
// ---------------------------------------------------------------------------
__global__ __launch_bounds__(256, 4) void bgemm_out(
    const bf16_t* __restrict__ A, const bf16_t* __restrict__ W,
    const float* __restrict__ bias, float* __restrict__ C, int N) {
  __shared__ bf16_t As[128 * 64];
  __shared__ bf16_t Bs[128 * 64];

  const int tid = threadIdx.x;
  const int wave = tid >> 6, lane = tid & 63;
  const int wr = wave >> 1, wc = wave & 1;
  const int bm = blockIdx.y * 128, bn = blockIdx.x * 128;
  const int q = lane >> 4, ln = lane & 15;
  const int grow = tid >> 3;
  const int gcol = ((tid & 7) ^ (grow & 7)) * 8;

  f32x4 acc[4][4];
#pragma unroll
  for (int mi = 0; mi < 4; ++mi)
#pragma unroll
    for (int ni = 0; ni < 4; ++ni)
#pragma unroll
      for (int r = 0; r < 4; ++r) acc[mi][ni][r] = 0.f;

  const int co[2] = {((q) ^ (ln & 7)) * 8, ((4 + q) ^ (ln & 7)) * 8};

  for (int k0 = 0; k0 < 1024; k0 += 64) {
    __syncthreads();
#pragma unroll
    for (int p = 0; p < 4; ++p) {
      GLL(&A[(size_t)(bm + p * 32 + grow) * 1024 + k0 + gcol], &As[p * 2048 + tid * 8]);
      GLL(&W[(size_t)(bn + p * 32 + grow) * 1024 + k0 + gcol], &Bs[p * 2048 + tid * 8]);
    }
    __syncthreads();
#pragma unroll
    for (int t = 0; t < 2; ++t) {
      bf16x8 af[4], bf[4];
#pragma unroll
      for (int mi = 0; mi < 4; ++mi)
        af[mi] = *(const bf16x8*)&As[(wr * 64 + mi * 16 + ln) * 64 + co[t]];
#pragma unroll
      for (int ni = 0; ni < 4; ++ni)
        bf[ni] = *(const bf16x8*)&Bs[(wc * 64 + ni * 16 + ln) * 64 + co[t]];
#pragma unroll
      for (int mi = 0; mi < 4; ++mi)
#pragma unroll
        for (int ni = 0; ni < 4; ++ni)
          acc[mi][ni] = __builtin_amdgcn_mfma_f32_16x16x32_bf16(
              af[mi], bf[ni], acc[mi][ni], 0, 0, 0);
    }
  }

#pragma unroll
  for (int mi = 0; mi < 4; ++mi) {
#pragma unroll
    for (int ni = 0; ni < 4; ++ni) {
      const int col = bn + wc * 64 + ni * 16 + ln;
      const float bv = bias[col];
#pragma unroll
      for (int r = 0; r < 4; ++r) {
        const int row = bm + wr * 64 + mi * 16 + q * 4 + r;
        C[(size_t)row * N + col] = acc[mi][ni][r] + bv;
      }
    }
  }
}

// ---------------------------------------------------------------------------
// MFMA flash attention, 3 streams merged per block — ALL z-indices are
// compile-time (R6's runtime z-loop demoted Od/aq to scratch: 227 MB spills).
// Grid (8, 64). Main K/V tiles staged once, used by z=0,1,2; two diagonal
// tiles handled in an unrolled epilogue loop. Fixed-shift softmax.
// launch_bounds(256,2): grid is 512 blocks = 2 blocks/CU; VGPR cap 256.
// ---------------------------------------------------------------------------
__global__ __launch_bounds__(256, 2) void flash_mfma(
    const bf16_t* __restrict__ qkvb, const bf16_t* __restrict__ vT,
    const float* __restrict__ relv2,
    const unsigned char* __restrict__ lutM, const unsigned char* __restrict__ lutP,
    bf16_t* __restrict__ attn) {
  __shared__ bf16_t Ks[64 * 64];
  __shared__ bf16_t Vts[64 * 64];
  __shared__ bf16_t Ps[4][16 * 64];
  __shared__ bf16_t biasS[3][64 * 33];
  __shared__ unsigned char lutMs[512];
  __shared__ unsigned char lutPs[512];

  const int qt = 7 - blockIdx.x, tq0 = qt * 64;
  const int bh = blockIdx.y, b = bh >> 4, h = bh & 15;
  const int tid = threadIdx.x;
  const int wave = tid >> 6, lane = tid & 63;
  const int q = lane >> 4, ln = lane & 15;
  const int m0 = wave * 16;
  const int grow = tid >> 3;
  const int gcol = ((tid & 7) ^ (grow & 7)) * 8;
  const int co[2] = {((q) ^ (ln & 7)) * 8, ((4 + q) ^ (ln & 7)) * 8};

  if (tid < 128) ((int*)lutMs)[tid] = ((const int*)lutM)[tid];
  else if (tid < 256) ((int*)lutPs)[tid - 128] = ((const int*)lutP)[tid - 128];

  // stage bias tables for all 3 streams (bf16, [z][row][bucket])
#pragma unroll
  for (int z = 0; z < 3; ++z) {
#pragma unroll
    for (int u = 0; u < 2; ++u) {
      const int c = u * 256 + tid;
      const int row = c >> 3, j4 = (c & 7) * 4;
      const float4 v = *(const float4*)
          &relv2[((size_t)(z * T_ + tq0 + row) * B_ + b) * 512 + h * 32 + j4];
      biasS[z][row * 33 + j4 + 0] = (bf16_t)v.x;
      biasS[z][row * 33 + j4 + 1] = (bf16_t)v.y;
      biasS[z][row * 33 + j4 + 2] = (bf16_t)v.z;
      biasS[z][row * 33 + j4 + 3] = (bf16_t)v.w;
    }
  }

  // stage Q for each stream through the Ks buffer, keep fragments in regs
  bf16x8 aq[3][2];
#pragma unroll
  for (int z = 0; z < 3; ++z) {
    __syncthreads();  // Ks free (also publishes biasS/luts on z=0)
#pragma unroll
    for (int u = 0; u < 2; ++u) {
      const int sr = u * 32 + grow;
      GLL(&qkvb[((size_t)(z * T_ + tq0 + sr) * B_ + b) * 3072 + h * 64 + gcol],
          &Ks[u * 2048 + tid * 8]);
    }
    __syncthreads();
    aq[z][0] = *(const bf16x8*)&Ks[(m0 + ln) * 64 + co[0]];
    aq[z][1] = *(const bf16x8*)&Ks[(m0 + ln) * 64 + co[1]];
  }

  f32x4 Od[3][4];
  float lpart[3][4];
#pragma unroll
  for (int z = 0; z < 3; ++z)
#pragma unroll
    for (int r = 0; r < 4; ++r) {
      lpart[z][r] = 0.f;
#pragma unroll
      for (int tc = 0; tc < 4; ++tc) Od[z][tc][r] = 0.f;
    }

  // ---- main tiles: staged once, consumed by all three streams ----
  for (int j = 0; j <= qt; ++j) {
    const int krb = j * 64;
    __syncthreads();  // prev tile consumers done with Ks/Vts
#pragma unroll
    for (int u = 0; u < 2; ++u) {
      const int sr = u * 32 + grow;
      GLL(&qkvb[((size_t)(krb + sr) * B_ + b) * 3072 + 1024 + h * 64 + gcol],
          &Ks[u * 2048 + tid * 8]);
      GLL(&vT[((size_t)bh * 64 + sr) * (size_t)TGT_ + krb + gcol],
          &Vts[u * 2048 + tid * 8]);
    }
    __syncthreads();

#pragma unroll
    for (int z = 0; z < 3; ++z) {
      // QK^T for stream z
      f32x4 acc[4];
#pragma unroll
      for (int tc = 0; tc < 4; ++tc)
#pragma unroll
        for (int r = 0; r < 4; ++r) acc[tc][r] = 0.f;
#pragma unroll
      for (int tc = 0; tc < 4; ++tc) {
        const bf16x8 b0 = *(const bf16x8*)&Ks[(tc * 16 + ln) * 64 + co[0]];
        acc[tc] = __builtin_amdgcn_mfma_f32_16x16x32_bf16(aq[z][0], b0, acc[tc], 0, 0, 0);
        const bf16x8 b1 = *(const bf16x8*)&Ks[(tc * 16 + ln) * 64 + co[1]];
        acc[tc] = __builtin_amdgcn_mfma_f32_16x16x32_bf16(aq[z][1], b1, acc[tc], 0, 0, 0);
      }

      // bias + mask + exp; write P (swizzled) into own-wave buffer
#pragma unroll
      for (int r = 0; r < 4; ++r) {
        const int rloc = m0 + q * 4 + r;
#pragma unroll
        for (int tc = 0; tc < 4; ++tc) {
          const int sl = tc * 16 + ln;
          const bool valid = (j < qt) | (sl <= rloc);
          int d = tq0 + rloc - (krb + sl);
          d = d < 0 ? 0 : d;
          const float bv =
              (float)biasS[z][rloc * 33 + (int)(z == 0 ? lutMs[d] : lutPs[d])];
          const float p = valid ? __expf(acc[tc][r] + bv) : 0.f;
          lpart[z][r] += p;
          const int pc = (tc * 2 + (ln >> 3)) ^ ((q * 4 + r) & 7);
          Ps[wave][(q * 4 + r) * 64 + pc * 8 + (ln & 7)] = (bf16_t)p;
        }
      }

      // O += P V (own-wave Ps: same-wave LDS ordering, no barrier)
      bf16x8 ap[2];
      ap[0] = *(const bf16x8*)&Ps[wave][ln * 64 + co[0]];
      ap[1] = *(const bf16x8*)&Ps[wave][ln * 64 + co[1]];
#pragma unroll
      for (int tc = 0; tc < 4; ++tc) {
        const bf16x8 v0 = *(const bf16x8*)&Vts[(tc * 16 + ln) * 64 + co[0]];
        Od[z][tc] = __builtin_amdgcn_mfma_f32_16x16x32_bf16(ap[0], v0, Od[z][tc], 0, 0, 0);
        const bf16x8 v1 = *(const bf16x8*)&Vts[(tc * 16 + ln) * 64 + co[1]];
        Od[z][tc] = __builtin_amdgcn_mfma_f32_16x16x32_bf16(ap[1], v1, Od[z][tc], 0, 0, 0);
      }
    }
  }

  // ---- diagonal predict tiles for z=1,2 (compile-time z) ----
#pragma unroll
  for (int z = 1; z <= 2; ++z) {
    const int krb = z * T_ + tq0;
    __syncthreads();
#pragma unroll
    for (int u = 0; u < 2; ++u) {
      const int sr = u * 32 + grow;
      GLL(&qkvb[((size_t)(krb + sr) * B_ + b) * 3072 + 1024 + h * 64 + gcol],
          &Ks[u * 2048 + tid * 8]);
      GLL(&vT[((size_t)bh * 64 + sr) * (size_t)TGT_ + krb + gcol],
          &Vts[u * 2048 + tid * 8]);
    }
    __syncthreads();

    f32x4 acc[4];
#pragma unroll
    for (int tc = 0; tc < 4; ++tc)
#pragma unroll
      for (int r = 0; r < 4; ++r) acc[tc][r] = 0.f;
#pragma unroll
    for (int tc = 0; tc < 4; ++tc) {
      const bf16x8 b0 = *(const bf16x8*)&Ks[(tc * 16 + ln) * 64 + co[0]];
      acc[tc] = __builtin_amdgcn_mfma_f32_16x16x32_bf16(aq[z][0], b0, acc[tc], 0, 0, 0);
      const bf16x8 b1 = *(const bf16x8*)&Ks[(tc * 16 + ln) * 64 + co[1]];
      acc[tc] = __builtin_amdgcn_mfma_f32_16x16x32_bf16(aq[z][1], b1, acc[tc], 0, 0, 0);
    }

#pragma unroll
    for (int r = 0; r < 4; ++r) {
      const int rloc = m0 + q * 4 + r;
#pragma unroll
      for (int tc = 0; tc < 4; ++tc) {
        const int sl = tc * 16 + ln;
        const bool valid = (sl == rloc);
        const float bv = (float)biasS[z][rloc * 33];  // bucket(0) == 0
        const float p = valid ? __expf(acc[tc][r] + bv) : 0.f;
        lpart[z][r] += p;
        const int pc = (tc * 2 + (ln >> 3)) ^ ((q * 4 + r) & 7);
        Ps[wave][(q * 4 + r) * 64 + pc * 8 + (ln & 7)] = (bf16_t)p;
      }
    }

    bf16x8 ap[2];
    ap[0] = *(const bf16x8*)&Ps[wave][ln * 64 + co[0]];
    ap[1] = *(const bf16x8*)&Ps[wave][ln * 64 + co[1]];
#pragma unroll
    for (int tc = 0; tc < 4; ++tc) {
      const bf16x8 v0 = *(const bf16x8*)&Vts[(tc * 16 + ln) * 64 + co[0]];
      Od[z][tc] = __builtin_amdgcn_mfma_f32_16x16x32_bf16(ap[0], v0, Od[z][tc], 0, 0, 0);
      const bf16x8 v1 = *(const bf16x8*)&Vts[(tc * 16 + ln) * 64 + co[1]];
      Od[z][tc] = __builtin_amdgcn_mfma_f32_16x16x32_bf16(ap[1], v1, Od[z][tc], 0, 0, 0);
    }
  }

  // epilogue: reduce row sums, normalize, store (per stream)
#pragma unroll
  for (int z = 0; z < 3; ++z) {
#pragma unroll
    for (int r = 0; r < 4; ++r) {
      float l = lpart[z][r];
      l += __shfl_xor(l, 1, 16);
      l += __shfl_xor(l, 2, 16);
      l += __shfl_xor(l, 4, 16);
      l += __shfl_xor(l, 8, 16);
      const float inv = 1.f / l;
      const size_t rowbase =
          ((size_t)(z * T_ + tq0 + m0 + q * 4 + r) * B_ + b) * (size_t)E_ + h * 64;
#pragma unroll
      for (int tc = 0; tc < 4; ++tc)
        attn[rowbase + tc * 16 + ln] = (bf16_t)(Od[z][tc][r] * inv);
    }
  }
}

// ---------------------------------------------------------------------------
extern "C" void kernel_launch(void* const* d_in, const int* in_sizes, int n_in,
                              void* d_out, int out_size, void* d_ws, size_t ws_size,
                              hipStream_t stream) {
  const float* query = (const float*)d_in[0];
  const float* ipw   = (const float*)d_in[1];
  const float* ipb   = (const float*)d_in[2];
  const float* relw  = (const float*)d_in[3];
  const float* relb  = (const float*)d_in[4];
  const float* outw  = (const float*)d_in[5];
  const float* outb  = (const float*)d_in[6];
  const int*   mbuck = (const int*)d_in[7];
  const int*   pbuck = (const int*)d_in[8];
  float* out = (float*)d_out;

  // workspace layout (ipwb and relwb adjacent -> combined [3584][1024] W)
  bf16_t* qkvb  = (bf16_t*)d_ws;                                 // 6144x3072
  float*  relv2 = (float*)(qkvb + (size_t)ROWS_ * 3 * E_);       // 6144x512 f32
  bf16_t* qb    = (bf16_t*)(relv2 + (size_t)ROWS_ * 512);        // 6144x1024
  bf16_t* ipwb  = qb + (size_t)ROWS_ * E_;                       // 3072x1024
  bf16_t* relwb = ipwb + (size_t)(3 * E_) * E_;                  // 512x1024 (adjacent!)
  bf16_t* outwb = relwb + (size_t)512 * E_;                      // 1024x1024
  bf16_t* attnb = outwb + (size_t)E_ * E_;                       // 6144x1024
  unsigned char* lutM = (unsigned char*)(attnb + (size_t)ROWS_ * E_);
  unsigned char* lutP = lutM + 512;
  bf16_t* vT = (bf16_t*)(lutP + 512);                            // 64x64x1536

  const dim3 blk(256);

  // 1) conversions + LUTs
  {
    const int ntot = (ROWS_ * E_ + 3 * E_ * E_ + 512 * E_ + E_ * E_) / 4;
    prep<<<dim3((ntot + 255) / 256), blk, 0, stream>>>(
        query, ipw, relw, outw, qb, ipwb, relwb, outwb, mbuck, pbuck, lutM, lutP);
  }

  // 2) combined QKV + rel projection
  bgemm_proj<<<dim3(3584 / 128, ROWS_ / 128), blk, 0, stream>>>(
      qb, ipwb, ipb, relb, qkvb, relv2);

  // 3) V stream transpose
  transpose_v<<<dim3(TGT_ / 64, B_ * H_), blk, 0, stream>>>(qkvb, vT);

  // 4) flash attention, all streams merged
  flash_mfma<<<dim3(8, B_ * H_), blk, 0, stream>>>(
      qkvb, vT, relv2, lutM, lutP, attnb);

  // 5) output projection
  bgemm_out<<<dim3(E_ / 128, ROWS_ / 128), blk, 0, stream>>>(
      attnb, outwb, outb, out, E_);
}

// Round 9
// 244.312 us; speedup vs baseline: 1.4687x; 1.0458x over previous
//
#include <hip/hip_runtime.h>
#include <hip/hip_bf16.h>
#include <math.h>

// Problem constants
constexpr int T_ = 512;
constexpr int B_ = 4;
constexpr int E_ = 1024;
constexpr int H_ = 16;
constexpr int NGRAM_ = 2;
constexpr int TGT_ = (1 + NGRAM_) * T_;   // 1536
constexpr int ROWS_ = TGT_ * B_;          // 6144

typedef __bf16 bf16_t;
typedef __bf16 bf16x8 __attribute__((ext_vector_type(8)));
typedef __bf16 bf16x4 __attribute__((ext_vector_type(4)));
typedef float f32x4 __attribute__((ext_vector_type(4)));

#define GLL(gaddr, laddr)                                                     \
  __builtin_amdgcn_global_load_lds(                                           \
      (const __attribute__((address_space(1))) void*)(gaddr),                 \
      (__attribute__((address_space(3))) void*)(laddr), 16, 0, 0)

// ---------------------------------------------------------------------------
// prep: all fp32->bf16 conversions, one launch.
// ---------------------------------------------------------------------------
__global__ __launch_bounds__(256) void prep(
    const float* __restrict__ query, const float* __restrict__ ipw,
    const float* __restrict__ relw, const float* __restrict__ outw,
    bf16_t* __restrict__ qb, bf16_t* __restrict__ ipwb,
    bf16_t* __restrict__ relwb, bf16_t* __restrict__ outwb) {
  const int i = blockIdx.x * 256 + threadIdx.x;
  constexpr int N1 = ROWS_ * E_ / 4;
  constexpr int N2 = 3 * E_ * E_ / 4;
  constexpr int N3 = 512 * E_ / 4;
  constexpr int N4 = E_ * E_ / 4;
  const float4* src;
  bf16_t* dst;
  int j = i;
  if (i < N1) { src = (const float4*)query; dst = qb; }
  else if (i < N1 + N2) { src = (const float4*)ipw; dst = ipwb; j = i - N1; }
  else if (i < N1 + N2 + N3) { src = (const float4*)relw; dst = relwb; j = i - N1 - N2; }
  else if (i < N1 + N2 + N3 + N4) { src = (const float4*)outw; dst = outwb; j = i - N1 - N2 - N3; }
  else return;
  const float4 v = src[j];
  bf16x4 o;
  o[0] = (bf16_t)v.x; o[1] = (bf16_t)v.y;
  o[2] = (bf16_t)v.z; o[3] = (bf16_t)v.w;
  ((bf16x4*)dst)[j] = o;
}

// ---------------------------------------------------------------------------
// Combined projection GEMM: A[6144][1024] bf16, W[3584][1024] bf16.
// Epilogue routing:
//   bn < 1024       : qkvb bf16 * 0.125 (Q)
//   bn < 2048       : qkvb bf16 (K)
//   bn < 3072       : vT bf16 (V, transposed in-block via swizzled LDS bounce)
//   else            : relv2 fp32 [row][h*32+bk]
// ---------------------------------------------------------------------------
__device__ __forceinline__ int lt_sw(int row, int col) {
  return row * 128 + ((((col >> 3) ^ (row & 15)) << 3) | (col & 7));
}

__global__ __launch_bounds__(256, 4) void bgemm_proj(
    const bf16_t* __restrict__ A, const bf16_t* __restrict__ W,
    const float* __restrict__ ipb, const float* __restrict__ relb,
    bf16_t* __restrict__ qkvb, float* __restrict__ relv2,
    bf16_t* __restrict__ vT) {
  __shared__ bf16_t smem[2 * 128 * 64];  // As | Bs ; aliased as Lt[128][128]
  bf16_t* As = smem;
  bf16_t* Bs = smem + 128 * 64;

  const int tid = threadIdx.x;
  const int wave = tid >> 6, lane = tid & 63;
  const int wr = wave >> 1, wc = wave & 1;
  const int bm = blockIdx.y * 128, bn = blockIdx.x * 128;
  const int q = lane >> 4, ln = lane & 15;
  const int grow = tid >> 3;
  const int gcol = ((tid & 7) ^ (grow & 7)) * 8;

  f32x4 acc[4][4];
#pragma unroll
  for (int mi = 0; mi < 4; ++mi)
#pragma unroll
    for (int ni = 0; ni < 4; ++ni)
#pragma unroll
      for (int r = 0; r < 4; ++r) acc[mi][ni][r] = 0.f;

  const int co[2] = {((q) ^ (ln & 7)) * 8, ((4 + q) ^ (ln & 7)) * 8};

  for (int k0 = 0; k0 < 1024; k0 += 64) {
    __syncthreads();
#pragma unroll
    for (int p = 0; p < 4; ++p) {
      GLL(&A[(size_t)(bm + p * 32 + grow) * 1024 + k0 + gcol], &As[p * 2048 + tid * 8]);
      GLL(&W[(size_t)(bn + p * 32 + grow) * 1024 + k0 + gcol], &Bs[p * 2048 + tid * 8]);
    }
    __syncthreads();
#pragma unroll
    for (int t = 0; t < 2; ++t) {
      bf16x8 af[4], bf[4];
#pragma unroll
      for (int mi = 0; mi < 4; ++mi)
        af[mi] = *(const bf16x8*)&As[(wr * 64 + mi * 16 + ln) * 64 + co[t]];
#pragma unroll
      for (int ni = 0; ni < 4; ++ni)
        bf[ni] = *(const bf16x8*)&Bs[(wc * 64 + ni * 16 + ln) * 64 + co[t]];
#pragma unroll
      for (int mi = 0; mi < 4; ++mi)
#pragma unroll
        for (int ni = 0; ni < 4; ++ni)
          acc[mi][ni] = __builtin_amdgcn_mfma_f32_16x16x32_bf16(
              af[mi], bf[ni], acc[mi][ni], 0, 0, 0);
    }
  }

  if (bn < 2048) {
    // Q (scaled) and K -> qkvb
    const float sc = (bn < 1024) ? 0.125f : 1.0f;
#pragma unroll
    for (int mi = 0; mi < 4; ++mi) {
#pragma unroll
      for (int ni = 0; ni < 4; ++ni) {
        const int col = bn + wc * 64 + ni * 16 + ln;
        const float bv = ipb[col];
#pragma unroll
        for (int r = 0; r < 4; ++r) {
          const int row = bm + wr * 64 + mi * 16 + q * 4 + r;
          qkvb[(size_t)row * 3072 + col] = (bf16_t)((acc[mi][ni][r] + bv) * sc);
        }
      }
    }
  } else if (bn < 3072) {
    // V: transpose in-block, write vT[bh][d][token]
    __syncthreads();  // done with As/Bs staging reads
#pragma unroll
    for (int mi = 0; mi < 4; ++mi) {
#pragma unroll
      for (int ni = 0; ni < 4; ++ni) {
        const int col_l = wc * 64 + ni * 16 + ln;
        const float bv = ipb[bn + col_l];
#pragma unroll
        for (int r = 0; r < 4; ++r) {
          const int row_l = wr * 64 + mi * 16 + q * 4 + r;
          smem[lt_sw(row_l, col_l)] = (bf16_t)(acc[mi][ni][r] + bv);
        }
      }
    }
    __syncthreads();
    const int h0 = (bn - 2048) >> 6;
    const int tb0 = bm >> 2;
#pragma unroll
    for (int e = 0; e < 2; ++e) {
      const int task = tid + e * 256;      // 512 tasks: (b, col)
      const int b = task & 3;
      const int c = task >> 2;             // 0..127
      const int h = h0 + (c >> 6);
      const int d = c & 63;
      const size_t base = ((size_t)((b * 16 + h) * 64 + d)) * (size_t)TGT_ + tb0;
#pragma unroll
      for (int c4 = 0; c4 < 4; ++c4) {
        bf16x8 v8;
#pragma unroll
        for (int i = 0; i < 8; ++i)
          v8[i] = smem[lt_sw((c4 * 8 + i) * 4 + b, c)];
        *(bf16x8*)&vT[base + c4 * 8] = v8;
      }
    }
  } else {
    const int cb = bn - 3072 + wc * 64;
    float4 rb4;
#pragma unroll
    for (int ni = 0; ni < 4; ++ni)
      ((float*)&rb4)[ni] = relb[cb + ni * 16 + ln];
    const int bkbase = cb >> 4;
#pragma unroll
    for (int mi = 0; mi < 4; ++mi) {
#pragma unroll
      for (int r = 0; r < 4; ++r) {
        const int row = bm + wr * 64 + mi * 16 + q * 4 + r;
        float4 v;
        v.x = acc[mi][0][r] + rb4.x;
        v.y = acc[mi][1][r] + rb4.y;
        v.z = acc[mi][2][r] + rb4.z;
        v.w = acc[mi][3][r] + rb4.w;
        *(float4*)&relv2[(size_t)row * 512 + ln * 32 + bkbase] = v;
      }
    }
  }
}

// ---------------------------------------------------------------------------
// Output projection GEMM (fp32 out).
// ---------------------------------------------------------------------------
__global__ __launch_bounds__(256, 4) void bgemm_out(
    const bf16_t* __restrict__ A, const bf16_t* __restrict__ W,
    const float* __restrict__ bias, float* __restrict__ C, int N) {
  __shared__ bf16_t As[128 * 64];
  __shared__ bf16_t Bs[128 * 64];

  const int tid = threadIdx.x;
  const int wave = tid >> 6, lane = tid & 63;
  const int wr = wave >> 1, wc = wave & 1;
  const int bm = blockIdx.y * 128, bn = blockIdx.x * 128;
  const int q = lane >> 4, ln = lane & 15;
  const int grow = tid >> 3;
  const int gcol = ((tid & 7) ^ (grow & 7)) * 8;

  f32x4 acc[4][4];
#pragma unroll
  for (int mi = 0; mi < 4; ++mi)
#pragma unroll
    for (int ni = 0; ni < 4; ++ni)
#pragma unroll
      for (int r = 0; r < 4; ++r) acc[mi][ni][r] = 0.f;

  const int co[2] = {((q) ^ (ln & 7)) * 8, ((4 + q) ^ (ln & 7)) * 8};

  for (int k0 = 0; k0 < 1024; k0 += 64) {
    __syncthreads();
#pragma unroll
    for (int p = 0; p < 4; ++p) {
      GLL(&A[(size_t)(bm + p * 32 + grow) * 1024 + k0 + gcol], &As[p * 2048 + tid * 8]);
      GLL(&W[(size_t)(bn + p * 32 + grow) * 1024 + k0 + gcol], &Bs[p * 2048 + tid * 8]);
    }
    __syncthreads();
#pragma unroll
    for (int t = 0; t < 2; ++t) {
      bf16x8 af[4], bf[4];
#pragma unroll
      for (int mi = 0; mi < 4; ++mi)
        af[mi] = *(const bf16x8*)&As[(wr * 64 + mi * 16 + ln) * 64 + co[t]];
#pragma unroll
      for (int ni = 0; ni < 4; ++ni)
        bf[ni] = *(const bf16x8*)&Bs[(wc * 64 + ni * 16 + ln) * 64 + co[t]];
#pragma unroll
      for (int mi = 0; mi < 4; ++mi)
#pragma unroll
        for (int ni = 0; ni < 4; ++ni)
          acc[mi][ni] = __builtin_amdgcn_mfma_f32_16x16x32_bf16(
              af[mi], bf[ni], acc[mi][ni], 0, 0, 0);
    }
  }

#pragma unroll
  for (int mi = 0; mi < 4; ++mi) {
#pragma unroll
    for (int ni = 0; ni < 4; ++ni) {
      const int col = bn + wc * 64 + ni * 16 + ln;
      const float bv = bias[col];
#pragma unroll
      for (int r = 0; r < 4; ++r) {
        const int row = bm + wr * 64 + mi * 16 + q * 4 + r;
        C[(size_t)row * N + col] = acc[mi][ni][r] + bv;
      }
    }
  }
}

// ---------------------------------------------------------------------------
// MFMA flash attention, 3 streams merged, double-buffered K/V staging,
// K/V fragments hoisted out of the z-loop, VALU-computed bucket (no LUT),
// far tiles (d>=113 -> bucket==31) use per-row register bias.
// Grid (8, 64). One barrier per tile. All register arrays statically indexed.
// ---------------------------------------------------------------------------
__device__ __forceinline__ int bucket_of(int n) {
  // reference: n<16 -> n; else min(31, int(16 + ln(n/16)/ln(8)*16))
  if (n < 16) return n;
  const float lf = __log2f((float)n);
  int b = (int)(16.0f + (lf - 4.0f) * 5.3333333f);
  return b > 31 ? 31 : b;
}

__global__ __launch_bounds__(256, 2) void flash_mfma(
    const bf16_t* __restrict__ qkvb, const bf16_t* __restrict__ vT,
    const float* __restrict__ relv2, bf16_t* __restrict__ attn) {
  __shared__ bf16_t Ks[2][64 * 64];
  __shared__ bf16_t Vts[2][64 * 64];
  __shared__ bf16_t Ps[4][16 * 64];
  __shared__ bf16_t biasS[3][64 * 33];

  const int qt = 7 - blockIdx.x, tq0 = qt * 64;
  const int bh = blockIdx.y, b = bh >> 4, h = bh & 15;
  const int tid = threadIdx.x;
  const int wave = tid >> 6, lane = tid & 63;
  const int q = lane >> 4, ln = lane & 15;
  const int m0 = wave * 16;
  const int grow = tid >> 3;
  const int gcol = ((tid & 7) ^ (grow & 7)) * 8;
  const int co[2] = {((q) ^ (ln & 7)) * 8, ((4 + q) ^ (ln & 7)) * 8};

  // stage bias tables for all 3 streams
#pragma unroll
  for (int z = 0; z < 3; ++z) {
#pragma unroll
    for (int u = 0; u < 2; ++u) {
      const int c = u * 256 + tid;
      const int row = c >> 3, j4 = (c & 7) * 4;
      const float4 v = *(const float4*)
          &relv2[((size_t)(z * T_ + tq0 + row) * B_ + b) * 512 + h * 32 + j4];
      biasS[z][row * 33 + j4 + 0] = (bf16_t)v.x;
      biasS[z][row * 33 + j4 + 1] = (bf16_t)v.y;
      biasS[z][row * 33 + j4 + 2] = (bf16_t)v.z;
      biasS[z][row * 33 + j4 + 3] = (bf16_t)v.w;
    }
  }

  // stage all three Q tiles into the 3 spare buffers (one barrier)
#pragma unroll
  for (int u = 0; u < 2; ++u) {
    const int sr = u * 32 + grow;
    GLL(&qkvb[((size_t)(0 * T_ + tq0 + sr) * B_ + b) * 3072 + h * 64 + gcol],
        &Ks[0][u * 2048 + tid * 8]);
    GLL(&qkvb[((size_t)(1 * T_ + tq0 + sr) * B_ + b) * 3072 + h * 64 + gcol],
        &Vts[0][u * 2048 + tid * 8]);
    GLL(&qkvb[((size_t)(2 * T_ + tq0 + sr) * B_ + b) * 3072 + h * 64 + gcol],
        &Ks[1][u * 2048 + tid * 8]);
  }
  __syncthreads();

  bf16x8 aq[3][2];
  aq[0][0] = *(const bf16x8*)&Ks[0][(m0 + ln) * 64 + co[0]];
  aq[0][1] = *(const bf16x8*)&Ks[0][(m0 + ln) * 64 + co[1]];
  aq[1][0] = *(const bf16x8*)&Vts[0][(m0 + ln) * 64 + co[0]];
  aq[1][1] = *(const bf16x8*)&Vts[0][(m0 + ln) * 64 + co[1]];
  aq[2][0] = *(const bf16x8*)&Ks[1][(m0 + ln) * 64 + co[0]];
  aq[2][1] = *(const bf16x8*)&Ks[1][(m0 + ln) * 64 + co[1]];

  // per-row register biases: far-tile (bucket 31) and diagonal (bucket 0)
  float bv31[3][4], bv0[3][4];
#pragma unroll
  for (int z = 0; z < 3; ++z)
#pragma unroll
    for (int r = 0; r < 4; ++r) {
      const int rloc = m0 + q * 4 + r;
      bv31[z][r] = (float)biasS[z][rloc * 33 + 31];
      bv0[z][r] = (float)biasS[z][rloc * 33];
    }

  f32x4 Od[3][4];
  float lpart[3][4];
#pragma unroll
  for (int z = 0; z < 3; ++z)
#pragma unroll
    for (int r = 0; r < 4; ++r) {
      lpart[z][r] = 0.f;
#pragma unroll
      for (int tc = 0; tc < 4; ++tc) Od[z][tc][r] = 0.f;
    }

  const int ntiles = qt + 3;

  auto stage_tile = [&](int jj, int buf) {
    const int krb = (jj <= qt) ? jj * 64 : ((jj - qt) * T_ + tq0);
#pragma unroll
    for (int u = 0; u < 2; ++u) {
      const int sr = u * 32 + grow;
      GLL(&qkvb[((size_t)(krb + sr) * B_ + b) * 3072 + 1024 + h * 64 + gcol],
          &Ks[buf][u * 2048 + tid * 8]);
      GLL(&vT[((size_t)bh * 64 + sr) * (size_t)TGT_ + krb + gcol],
          &Vts[buf][u * 2048 + tid * 8]);
    }
  };

  __syncthreads();          // aq reads complete before overwriting buffers
  stage_tile(0, 0);
  __syncthreads();          // tile 0 resident

  for (int jj = 0; jj < ntiles; ++jj) {
    const int cur = jj & 1;
    if (jj + 1 < ntiles) stage_tile(jj + 1, cur ^ 1);  // async prefetch

    const int krb = (jj <= qt) ? jj * 64 : ((jj - qt) * T_ + tq0);

    // hoisted K/V fragments (read once, used by all streams)
    bf16x8 kf[4][2], vf[4][2];
#pragma unroll
    for (int tc = 0; tc < 4; ++tc) {
      kf[tc][0] = *(const bf16x8*)&Ks[cur][(tc * 16 + ln) * 64 + co[0]];
      kf[tc][1] = *(const bf16x8*)&Ks[cur][(tc * 16 + ln) * 64 + co[1]];
      vf[tc][0] = *(const bf16x8*)&Vts[cur][(tc * 16 + ln) * 64 + co[0]];
      vf[tc][1] = *(const bf16x8*)&Vts[cur][(tc * 16 + ln) * 64 + co[1]];
    }

    if (jj <= qt) {
      const bool far = (jj <= qt - 3);  // all d >= 113 -> bucket == 31
#pragma unroll
      for (int z = 0; z < 3; ++z) {
        f32x4 acc[4];
#pragma unroll
        for (int tc = 0; tc < 4; ++tc)
#pragma unroll
          for (int r = 0; r < 4; ++r) acc[tc][r] = 0.f;
#pragma unroll
        for (int tc = 0; tc < 4; ++tc) {
          acc[tc] = __builtin_amdgcn_mfma_f32_16x16x32_bf16(aq[z][0], kf[tc][0], acc[tc], 0, 0, 0);
          acc[tc] = __builtin_amdgcn_mfma_f32_16x16x32_bf16(aq[z][1], kf[tc][1], acc[tc], 0, 0, 0);
        }

        if (far) {
#pragma unroll
          for (int r = 0; r < 4; ++r) {
            const float bv = bv31[z][r];
#pragma unroll
            for (int tc = 0; tc < 4; ++tc) {
              const float p = __expf(acc[tc][r] + bv);
              lpart[z][r] += p;
              const int pc = (tc * 2 + (ln >> 3)) ^ ((q * 4 + r) & 7);
              Ps[wave][(q * 4 + r) * 64 + pc * 8 + (ln & 7)] = (bf16_t)p;
            }
          }
        } else {
#pragma unroll
          for (int r = 0; r < 4; ++r) {
            const int rloc = m0 + q * 4 + r;
            const int dbase = tq0 + rloc - krb;
#pragma unroll
            for (int tc = 0; tc < 4; ++tc) {
              const int sl = tc * 16 + ln;
              const int d = dbase - sl;
              const bool valid = (jj < qt) | (d >= 0);
              int n = d < 0 ? 0 : d;
              if (z > 0) n += 1;
              const float bv = (float)biasS[z][rloc * 33 + bucket_of(n)];
              const float p = valid ? __expf(acc[tc][r] + bv) : 0.f;
              lpart[z][r] += p;
              const int pc = (tc * 2 + (ln >> 3)) ^ ((q * 4 + r) & 7);
              Ps[wave][(q * 4 + r) * 64 + pc * 8 + (ln & 7)] = (bf16_t)p;
            }
          }
        }

        bf16x8 ap[2];
        ap[0] = *(const bf16x8*)&Ps[wave][ln * 64 + co[0]];
        ap[1] = *(const bf16x8*)&Ps[wave][ln * 64 + co[1]];
#pragma unroll
        for (int tc = 0; tc < 4; ++tc) {
          Od[z][tc] = __builtin_amdgcn_mfma_f32_16x16x32_bf16(ap[0], vf[tc][0], Od[z][tc], 0, 0, 0);
          Od[z][tc] = __builtin_amdgcn_mfma_f32_16x16x32_bf16(ap[1], vf[tc][1], Od[z][tc], 0, 0, 0);
        }
      }
    } else {
      // diagonal predict tile: only stream z == jj - qt
#pragma unroll
      for (int z = 1; z <= 2; ++z) {
        if (jj - qt == z) {
          f32x4 acc[4];
#pragma unroll
          for (int tc = 0; tc < 4; ++tc)
#pragma unroll
            for (int r = 0; r < 4; ++r) acc[tc][r] = 0.f;
#pragma unroll
          for (int tc = 0; tc < 4; ++tc) {
            acc[tc] = __builtin_amdgcn_mfma_f32_16x16x32_bf16(aq[z][0], kf[tc][0], acc[tc], 0, 0, 0);
            acc[tc] = __builtin_amdgcn_mfma_f32_16x16x32_bf16(aq[z][1], kf[tc][1], acc[tc], 0, 0, 0);
          }
#pragma unroll
          for (int r = 0; r < 4; ++r) {
            const int rloc = m0 + q * 4 + r;
            const float bv = bv0[z][r];
#pragma unroll
            for (int tc = 0; tc < 4; ++tc) {
              const int sl = tc * 16 + ln;
              const float p = (sl == rloc) ? __expf(acc[tc][r] + bv) : 0.f;
              lpart[z][r] += p;
              const int pc = (tc * 2 + (ln >> 3)) ^ ((q * 4 + r) & 7);
              Ps[wave][(q * 4 + r) * 64 + pc * 8 + (ln & 7)] = (bf16_t)p;
            }
          }
          bf16x8 ap[2];
          ap[0] = *(const bf16x8*)&Ps[wave][ln * 64 + co[0]];
          ap[1] = *(const bf16x8*)&Ps[wave][ln * 64 + co[1]];
#pragma unroll
          for (int tc = 0; tc < 4; ++tc) {
            Od[z][tc] = __builtin_amdgcn_mfma_f32_16x16x32_bf16(ap[0], vf[tc][0], Od[z][tc], 0, 0, 0);
            Od[z][tc] = __builtin_amdgcn_mfma_f32_16x16x32_bf16(ap[1], vf[tc][1], Od[z][tc], 0, 0, 0);
          }
        }
      }
    }
    __syncthreads();  // readers done with cur; prefetch (cur^1) drained
  }

  // epilogue: reduce row sums, normalize, store
#pragma unroll
  for (int z = 0; z < 3; ++z) {
#pragma unroll
    for (int r = 0; r < 4; ++r) {
      float l = lpart[z][r];
      l += __shfl_xor(l, 1, 16);
      l += __shfl_xor(l, 2, 16);
      l += __shfl_xor(l, 4, 16);
      l += __shfl_xor(l, 8, 16);
      const float inv = 1.f / l;
      const size_t rowbase =
          ((size_t)(z * T_ + tq0 + m0 + q * 4 + r) * B_ + b) * (size_t)E_ + h * 64;
#pragma unroll
      for (int tc = 0; tc < 4; ++tc)
        attn[rowbase + tc * 16 + ln] = (bf16_t)(Od[z][tc][r] * inv);
    }
  }
}

// ---------------------------------------------------------------------------
extern "C" void kernel_launch(void* const* d_in, const int* in_sizes, int n_in,
                              void* d_out, int out_size, void* d_ws, size_t ws_size,
                              hipStream_t stream) {
  const float* query = (const float*)d_in[0];
  const float* ipw   = (const float*)d_in[1];
  const float* ipb   = (const float*)d_in[2];
  const float* relw  = (const float*)d_in[3];
  const float* relb  = (const float*)d_in[4];
  const float* outw  = (const float*)d_in[5];
  const float* outb  = (const float*)d_in[6];
  float* out = (float*)d_out;

  // workspace layout (ipwb and relwb adjacent -> combined [3584][1024] W)
  bf16_t* qkvb  = (bf16_t*)d_ws;                                 // 6144x3072
  float*  relv2 = (float*)(qkvb + (size_t)ROWS_ * 3 * E_);       // 6144x512 f32
  bf16_t* qb    = (bf16_t*)(relv2 + (size_t)ROWS_ * 512);        // 6144x1024
  bf16_t* ipwb  = qb + (size_t)ROWS_ * E_;                       // 3072x1024
  bf16_t* relwb = ipwb + (size_t)(3 * E_) * E_;                  // 512x1024 (adjacent!)
  bf16_t* outwb = relwb + (size_t)512 * E_;                      // 1024x1024
  bf16_t* attnb = outwb + (size_t)E_ * E_;                       // 6144x1024
  bf16_t* vT    = attnb + (size_t)ROWS_ * E_;                    // 64x64x1536

  const dim3 blk(256);

  // 1) conversions
  {
    const int ntot = (ROWS_ * E_ + 3 * E_ * E_ + 512 * E_ + E_ * E_) / 4;
    prep<<<dim3((ntot + 255) / 256), blk, 0, stream>>>(
        query, ipw, relw, outw, qb, ipwb, relwb, outwb);
  }

  // 2) combined QKV + rel projection (V written transposed to vT)
  bgemm_proj<<<dim3(3584 / 128, ROWS_ / 128), blk, 0, stream>>>(
      qb, ipwb, ipb, relb, qkvb, relv2, vT);

  // 3) flash attention, all streams merged
  flash_mfma<<<dim3(8, B_ * H_), blk, 0, stream>>>(
      qkvb, vT, relv2, attnb);

  // 4) output projection
  bgemm_out<<<dim3(E_ / 128, ROWS_ / 128), blk, 0, stream>>>(
      attnb, outwb, outb, out, E_);
}